// Round 4
// baseline (178.519 us; speedup 1.0000x reference)
//
#include <hip/hip_runtime.h>

#define N_NODES 50000
#define N_EDGES 800000
#define D_IN    256
#define D_OUT   128
#define ELL_S   64                         // ELL stride; P(deg>=64)~1e-18 for Poisson(16)
#define GEMM_BLKS ((N_NODES + 127) / 128)  // 391
#define BKT_BLKS  (N_EDGES / 256)          // 3125 exactly (800000 = 3125*256)
#define CS        16                       // cnt stride in ints: 1 counter per 64B line.
                                           // THE experiment of this round: 800K returning
                                           // atomics were invariant ~54us across 3 scatter
                                           // structures; suspect same-line atomic
                                           // serialization (256 RMW ops/line when dense).
#define CNT_PAD   50176                    // counters (units of CS ints); 784 zero-blocks
#define ZERO_BLKS 784                      // 784*256 threads * 4 ints = 50176*16 ints

typedef __attribute__((ext_vector_type(8))) short short8;
typedef __attribute__((ext_vector_type(4))) float floatx4;

__device__ __forceinline__ unsigned short f2bf(float f) {
    unsigned int u = __float_as_uint(f);
    unsigned int r = (u + 0x7fffu + ((u >> 16) & 1u)) >> 16;   // RNE
    return (unsigned short)r;
}
__device__ __forceinline__ unsigned int pack2(float a, float b) {
    return (unsigned int)f2bf(a) | ((unsigned int)f2bf(b) << 16);
}
__device__ __forceinline__ float bfl(unsigned int u) { return __uint_as_float(u << 16); }
__device__ __forceinline__ float bfh(unsigned int u) { return __uint_as_float(u & 0xffff0000u); }

__device__ __forceinline__ int load_idx(const void* ei, int i, int is64) {
    if (is64) return (int)((const long long*)ei)[i];
    return ((const int*)ei)[i];
}

// ---------------------------------------------------------------------------
// D1 prep (fat): block 0 = edge-dtype detect; blocks 1..16 = W fragment pack;
// blocks 17..800 = zero padded cnt (3.2 MB). All independent.
//   wfrag layout: bf[((ct*8+kc)*64+lane)*8 + j] =
//                 bf16(W[kc*32 + (lane>>4)*8 + j][ct*16 + (lane&15)])
// ---------------------------------------------------------------------------
__global__ __launch_bounds__(256) void prep_kernel(const unsigned int* __restrict__ e,
                                                   int* __restrict__ is64,
                                                   const float* __restrict__ W,
                                                   unsigned short* __restrict__ bf,
                                                   int* __restrict__ cnt) {
    int bid = blockIdx.x;
    int tid = threadIdx.x;
    if (bid == 0) {
        __shared__ int found32;
        if (tid == 0) found32 = 0;
        __syncthreads();
        for (int i = tid; i < 2048; i += 256)
            if (e[2 * i + 1] != 0u) found32 = 1;
        __syncthreads();
        if (tid == 0) *is64 = (found32 ? 0 : 1);
    } else if (bid <= 16) {
        int g = (bid - 1) * 256 + tid;     // 0..4095
        int lane = g & 63;
        int kc   = (g >> 6) & 7;
        int ct   = g >> 9;
        int n  = ct * 16 + (lane & 15);
        int kb = kc * 32 + ((lane >> 4) & 3) * 8;
        unsigned int p[4];
#pragma unroll
        for (int jj = 0; jj < 4; jj++) {
            float a = W[(size_t)(kb + 2 * jj + 0) * D_OUT + n];
            float b = W[(size_t)(kb + 2 * jj + 1) * D_OUT + n];
            p[jj] = pack2(a, b);
        }
        *(uint4*)&bf[(size_t)g * 8] = make_uint4(p[0], p[1], p[2], p[3]);
    } else {
        int i0 = ((bid - 17) * 256 + tid) * 4;   // < CNT_PAD*CS by construction
        *(int4*)&cnt[i0] = make_int4(0, 0, 0, 0);
    }
}

// ---------------------------------------------------------------------------
// D2 fat kernel: blocks [0, GEMM_BLKS) = bf16-MFMA GEMM (h = bf16(x@W));
// blocks [GEMM_BLKS, +BKT_BLKS) = ELL adjacency build, 1 edge/thread
// (round-0 structure EXACTLY; the only variable vs round 0 is cnt stride
// CS=16 -> one counter per 64B line). A/B: round-0 fused = 54.5 us.
// ---------------------------------------------------------------------------
__global__ __launch_bounds__(256) void fused_kernel(const float* __restrict__ x,
                                                    const unsigned short* __restrict__ bf,
                                                    unsigned short* __restrict__ h,
                                                    const void* __restrict__ ei,
                                                    const int* __restrict__ is64p,
                                                    int* __restrict__ cnt,
                                                    int* __restrict__ bucket) {
    __shared__ unsigned short As[128][40];   // gemm A-tile (10 KB), +8 pad
    int tid = threadIdx.x;

    if (blockIdx.x >= GEMM_BLKS) {
        // ---- ELL bucket scatter: 1 edge/thread, line-padded counters ----
        int e = (blockIdx.x - GEMM_BLKS) * 256 + tid;   // grid sized exactly
        int is64 = *is64p;
        int s = load_idx(ei, e, is64);
        int d = load_idx(ei, N_EDGES + e, is64);
        int pos = atomicAdd(&cnt[d * CS], 1);
        if (pos < ELL_S) bucket[d * ELL_S + pos] = s;
        return;
    }

    // ---- GEMM ----
    int row0 = blockIdx.x * 128;
    int w    = tid >> 6;
    int lane = tid & 63;
    int quad = lane >> 4;
    int l15  = lane & 15;

    floatx4 acc[2][8];
#pragma unroll
    for (int i = 0; i < 2; i++)
#pragma unroll
        for (int j = 0; j < 8; j++) acc[i][j] = (floatx4){0.f, 0.f, 0.f, 0.f};

    int srow  = tid >> 1;            // 0..127
    int shalf = (tid & 1) * 16;
    const float* xrow = x + (size_t)(row0 + srow) * D_IN;
    bool svalid = (row0 + srow) < N_NODES;

    for (int k0 = 0; k0 < D_IN; k0 += 32) {
        uint4 p0 = make_uint4(0, 0, 0, 0), p1 = make_uint4(0, 0, 0, 0);
        if (svalid) {
            const float* src = xrow + k0 + shalf;
            float4 f0 = *(const float4*)(src + 0);
            float4 f1 = *(const float4*)(src + 4);
            float4 f2 = *(const float4*)(src + 8);
            float4 f3 = *(const float4*)(src + 12);
            p0 = make_uint4(pack2(f0.x, f0.y), pack2(f0.z, f0.w),
                            pack2(f1.x, f1.y), pack2(f1.z, f1.w));
            p1 = make_uint4(pack2(f2.x, f2.y), pack2(f2.z, f2.w),
                            pack2(f3.x, f3.y), pack2(f3.z, f3.w));
        }
        __syncthreads();
        *(uint4*)&As[srow][shalf + 0] = p0;
        *(uint4*)&As[srow][shalf + 8] = p1;
        __syncthreads();

        short8 a0 = *(const short8*)&As[w * 32 + l15][quad * 8];
        short8 a1 = *(const short8*)&As[w * 32 + 16 + l15][quad * 8];
        int kc = k0 >> 5;
#pragma unroll
        for (int ct = 0; ct < 8; ct++) {
            short8 b = *(const short8*)&bf[(size_t)(((ct * 8 + kc) * 64 + lane)) * 8];
            acc[0][ct] = __builtin_amdgcn_mfma_f32_16x16x32_bf16(a0, b, acc[0][ct], 0, 0, 0);
            acc[1][ct] = __builtin_amdgcn_mfma_f32_16x16x32_bf16(a1, b, acc[1][ct], 0, 0, 0);
        }
    }

#pragma unroll
    for (int rt = 0; rt < 2; rt++) {
        int grow0 = row0 + w * 32 + rt * 16 + quad * 4;
#pragma unroll
        for (int r = 0; r < 4; r++) {
            int grow = grow0 + r;
            if (grow < N_NODES) {
#pragma unroll
                for (int ct = 0; ct < 8; ct++) {
                    h[(size_t)grow * D_OUT + ct * 16 + l15] = f2bf(acc[rt][ct][r]);
                }
            }
        }
    }
}

// ---------------------------------------------------------------------------
// D3 gather: 4 dst nodes per wave64 (16 lanes/node, 8 bf16 channels/lane via
// dwordx4 row loads -> each load instruction moves 1 KB serving 4 edges).
// ELL slots preloaded per 16-chunk with the w=0 trick: invalid slots get
// (s=0, w=0) so the edge loop runs to a wave-uniform bound (wave_max) with
// zero divergence; out-of-range slots FMA zero against the L1-hot row 0.
// cnt reads use the CS=16 line-padded stride (cnt array is L2/L3-resident).
// ---------------------------------------------------------------------------
#define GACC(U, F)                                      \
    a0 += bfl(U.x) * (F); a1 += bfh(U.x) * (F);         \
    a2 += bfl(U.y) * (F); a3 += bfh(U.y) * (F);         \
    a4 += bfl(U.z) * (F); a5 += bfh(U.z) * (F);         \
    a6 += bfl(U.w) * (F); a7 += bfh(U.w) * (F);

#define GBODY(SS, WW, KB)                                                         \
    {                                                                             \
        int lim = wave_max - (KB);                                                \
        if (lim > 16) lim = 16;                                                   \
        for (int k = 0; k < lim; k += 4) {                                        \
            int   s0 = __shfl((SS), gk + k + 0), s1 = __shfl((SS), gk + k + 1);   \
            int   s2 = __shfl((SS), gk + k + 2), s3 = __shfl((SS), gk + k + 3);   \
            float f0 = __shfl((WW), gk + k + 0), f1 = __shfl((WW), gk + k + 1);   \
            float f2 = __shfl((WW), gk + k + 2), f3 = __shfl((WW), gk + k + 3);   \
            uint4 u0 = *(const uint4*)(h + (size_t)s0 * D_OUT + co);              \
            uint4 u1 = *(const uint4*)(h + (size_t)s1 * D_OUT + co);              \
            uint4 u2 = *(const uint4*)(h + (size_t)s2 * D_OUT + co);              \
            uint4 u3 = *(const uint4*)(h + (size_t)s3 * D_OUT + co);              \
            GACC(u0, f0); GACC(u1, f1); GACC(u2, f2); GACC(u3, f3);               \
        }                                                                         \
    }

__global__ __launch_bounds__(256) void gather_kernel(
    const unsigned short* __restrict__ h, const int* __restrict__ cnt,
    const int* __restrict__ bucket, const float* __restrict__ bias,
    const float* __restrict__ pa, float* __restrict__ out) {
    int wave = (int)((blockIdx.x * blockDim.x + threadIdx.x) >> 6);
    int lane = threadIdx.x & 63;
    int g  = lane >> 4;            // node slot within wave (0..3)
    int l  = lane & 15;            // lane within node group
    int gk = g << 4;
    int d  = wave * 4 + g;         // N_NODES % 4 == 0 -> always valid
    if (wave >= N_NODES / 4) return;

    int nraw = cnt[d * CS];
    int n = nraw < ELL_S ? nraw : ELL_S;
    float di = rsqrtf((float)(nraw + 1));

    int co = l * 8;                // channel offset: 8 channels/lane (16 B)

    // self-loop: h[d] * di^2
    uint4 us = *(const uint4*)(h + (size_t)d * D_OUT + co);
    float sl = di * di;
    float a0 = bfl(us.x) * sl, a1 = bfh(us.x) * sl;
    float a2 = bfl(us.y) * sl, a3 = bfh(us.y) * sl;
    float a4 = bfl(us.z) * sl, a5 = bfh(us.z) * sl;
    float a6 = bfl(us.w) * sl, a7 = bfh(us.w) * sl;

    // preload ELL row: 4 chunks of 16 slots; invalid slots get (s=0, w=0)
    int db = d * ELL_S;
    int   s0v = 0,   s1v = 0,   s2v = 0,   s3v = 0;
    float w0v = 0.f, w1v = 0.f, w2v = 0.f, w3v = 0.f;
    if (l      < n) { s0v = bucket[db + l];      w0v = rsqrtf((float)(cnt[s0v * CS] + 1)) * di; }
    if (l + 16 < n) { s1v = bucket[db + l + 16]; w1v = rsqrtf((float)(cnt[s1v * CS] + 1)) * di; }
    if (l + 32 < n) { s2v = bucket[db + l + 32]; w2v = rsqrtf((float)(cnt[s2v * CS] + 1)) * di; }
    if (l + 48 < n) { s3v = bucket[db + l + 48]; w3v = rsqrtf((float)(cnt[s3v * CS] + 1)) * di; }

    // wave-wide max degree -> uniform loop bounds (no divergence in main loop)
    int wave_max = n;
    { int t = __shfl_xor(wave_max, 16); wave_max = t > wave_max ? t : wave_max; }
    { int t = __shfl_xor(wave_max, 32); wave_max = t > wave_max ? t : wave_max; }

    if (wave_max > 0)  GBODY(s0v, w0v, 0)
    if (wave_max > 16) GBODY(s1v, w1v, 16)
    if (wave_max > 32) GBODY(s2v, w2v, 32)
    if (wave_max > 48) GBODY(s3v, w3v, 48)

    int c = l * 8;
    float4 b0 = *(const float4*)&bias[c];
    float4 b1 = *(const float4*)&bias[c + 4];
    float4 p0 = *(const float4*)&pa[c];
    float4 p1 = *(const float4*)&pa[c + 4];
    float4 o0, o1;
    o0.x = a0 + b0.x; o0.y = a1 + b0.y; o0.z = a2 + b0.z; o0.w = a3 + b0.w;
    o1.x = a4 + b1.x; o1.y = a5 + b1.y; o1.z = a6 + b1.z; o1.w = a7 + b1.w;
    o0.x = o0.x > 0.f ? o0.x : p0.x * o0.x;
    o0.y = o0.y > 0.f ? o0.y : p0.y * o0.y;
    o0.z = o0.z > 0.f ? o0.z : p0.z * o0.z;
    o0.w = o0.w > 0.f ? o0.w : p0.w * o0.w;
    o1.x = o1.x > 0.f ? o1.x : p1.x * o1.x;
    o1.y = o1.y > 0.f ? o1.y : p1.y * o1.y;
    o1.z = o1.z > 0.f ? o1.z : p1.z * o1.z;
    o1.w = o1.w > 0.f ? o1.w : p1.w * o1.w;
    *(float4*)&out[(size_t)d * D_OUT + c]     = o0;
    *(float4*)&out[(size_t)d * D_OUT + c + 4] = o1;
}

extern "C" void kernel_launch(void* const* d_in, const int* in_sizes, int n_in,
                              void* d_out, int out_size, void* d_ws, size_t ws_size,
                              hipStream_t stream) {
    const float* x  = (const float*)d_in[0];
    const void*  ei = d_in[1];
    const float* W  = (const float*)d_in[2];
    const float* b  = (const float*)d_in[3];
    const float* pa = (const float*)d_in[4];
    float* out = (float*)d_out;

    char* w = (char*)d_ws;
    int*   is64   = (int*)w;    w += 256;
    int*   cnt    = (int*)w;    w += (size_t)CNT_PAD * CS * 4;            // 3.2 MB
    unsigned short* bfrag = (unsigned short*)w; w += 8 * 8 * 64 * 8 * 2;  // 64 KB
    int*   bucket = (int*)w;    w += (size_t)N_NODES * ELL_S * 4;         // 12.8 MB
    unsigned short* h = (unsigned short*)w; w += (size_t)N_NODES * D_OUT * 2;

    prep_kernel<<<1 + 16 + ZERO_BLKS, 256, 0, stream>>>((const unsigned int*)ei, is64, W, bfrag, cnt);
    fused_kernel<<<GEMM_BLKS + BKT_BLKS, 256, 0, stream>>>(x, bfrag, h, ei, is64, cnt, bucket);
    gather_kernel<<<(N_NODES / 4 * 64 + 255) / 256, 256, 0, stream>>>(h, cnt, bucket, b, pa, out);
}

// Round 5
// 164.881 us; speedup vs baseline: 1.0827x; 1.0827x over previous
//
#include <hip/hip_runtime.h>

#define N_NODES 50000
#define N_EDGES 800000
#define D_IN    256
#define D_OUT   128
#define ELL_S   64                         // ELL stride; P(deg>=64)~1e-18 for Poisson(16)
#define GEMM_BLKS ((N_NODES + 127) / 128)  // 391
#define NBINS   196                        // bins of 256 dsts: ceil(50000/256)
#define BCAP    5120                       // per-bin record cap; bin count ~Poisson(4082), +16 sigma
#define PART_BLKS 391                      // 391*2048 = 800768 >= 800000
#define EPB     2048                       // edges per partition block (8/thread)
#define CNT_N   (NBINS * 256)              // 50176 counters (dense, 1 int each)

typedef __attribute__((ext_vector_type(8))) short short8;
typedef __attribute__((ext_vector_type(4))) float floatx4;

__device__ __forceinline__ unsigned short f2bf(float f) {
    unsigned int u = __float_as_uint(f);
    unsigned int r = (u + 0x7fffu + ((u >> 16) & 1u)) >> 16;   // RNE
    return (unsigned short)r;
}
__device__ __forceinline__ unsigned int pack2(float a, float b) {
    return (unsigned int)f2bf(a) | ((unsigned int)f2bf(b) << 16);
}
__device__ __forceinline__ float bfl(unsigned int u) { return __uint_as_float(u << 16); }
__device__ __forceinline__ float bfh(unsigned int u) { return __uint_as_float(u & 0xffff0000u); }

// ---------------------------------------------------------------------------
// D1 prep: block 0 = edge-dtype detect; blocks 1..16 = W fragment pack;
// block 17 = zero binCur (196 ints). Nothing else needs zeroing: the
// partition matrix is fully written, cnt is fully written by ell_kernel,
// bucket is only read where pos < cnt.
// ---------------------------------------------------------------------------
__global__ __launch_bounds__(256) void prep_kernel(const unsigned int* __restrict__ e,
                                                   int* __restrict__ is64,
                                                   const float* __restrict__ W,
                                                   unsigned short* __restrict__ bf,
                                                   int* __restrict__ binCur) {
    int bid = blockIdx.x;
    int tid = threadIdx.x;
    if (bid == 0) {
        __shared__ int found32;
        if (tid == 0) found32 = 0;
        __syncthreads();
        for (int i = tid; i < 2048; i += 256)
            if (e[2 * i + 1] != 0u) found32 = 1;
        __syncthreads();
        if (tid == 0) *is64 = (found32 ? 0 : 1);
    } else if (bid <= 16) {
        // wfrag: bf[((ct*8+kc)*64+lane)*8+j] = bf16(W[kc*32+(lane>>4)*8+j][ct*16+(lane&15)])
        int g = (bid - 1) * 256 + tid;     // 0..4095
        int lane = g & 63;
        int kc   = (g >> 6) & 7;
        int ct   = g >> 9;
        int n  = ct * 16 + (lane & 15);
        int kb = kc * 32 + ((lane >> 4) & 3) * 8;
        unsigned int p[4];
#pragma unroll
        for (int jj = 0; jj < 4; jj++) {
            float a = W[(size_t)(kb + 2 * jj + 0) * D_OUT + n];
            float b = W[(size_t)(kb + 2 * jj + 1) * D_OUT + n];
            p[jj] = pack2(a, b);
        }
        *(uint4*)&bf[(size_t)g * 8] = make_uint4(p[0], p[1], p[2], p[3]);
    } else {
        if (tid < NBINS) binCur[tid] = 0;
    }
}

// ---------------------------------------------------------------------------
// D2 fat kernel: blocks [0, GEMM_BLKS) = bf16-MFMA GEMM (h = bf16(x@W));
// blocks [GEMM_BLKS, +PART_BLKS) = edge partition into 196 dst-bins.
//
// Round-4 finding: fused time (~54us) was INVARIANT to atomic line-sharing,
// XCD locality, MLP, and +-50% traffic -> the invariant was the COUNT of
// global returning atomics (800K ~ 54us, rate-limited at the coherence
// point). This version reduces global atomics 800K -> 391*196 ~ 77K:
// each block histograms its 2048 edges in LDS, reserves per-bin space with
// ONE global atomicAdd per (block,bin), then writes packed records
// (src | dst_local<<24) at reserved_base + LDS_rank. Bin segments have
// fixed capacity BCAP so no cross-bin prefix scan is needed.
// ---------------------------------------------------------------------------
__global__ __launch_bounds__(256) void fused_kernel(const float* __restrict__ x,
                                                    const unsigned short* __restrict__ bf,
                                                    unsigned short* __restrict__ h,
                                                    const void* __restrict__ ei,
                                                    const int* __restrict__ is64p,
                                                    int* __restrict__ binCur,
                                                    int* __restrict__ packed) {
    __shared__ unsigned short As[128][40];   // GEMM A-tile (10 KB), +8 pad
    __shared__ int hist[NBINS];
    __shared__ int curs[NBINS];
    int tid = threadIdx.x;

    if (blockIdx.x >= GEMM_BLKS) {
        // ---- partition ----
        int sb = blockIdx.x - GEMM_BLKS;
        for (int t = tid; t < NBINS; t += 256) hist[t] = 0;
        __syncthreads();
        int is64 = *is64p;
        int ebase = sb * EPB + tid;
        int sv[8], bn[8], dl[8], lr[8];
        if (is64) {
            const long long* p = (const long long*)ei;
#pragma unroll
            for (int i = 0; i < 8; i++) {
                int e = ebase + i * 256;
                if (e < N_EDGES) {
                    sv[i] = (int)p[e];
                    int d = (int)p[N_EDGES + e];
                    bn[i] = d >> 8; dl[i] = d & 255;
                } else bn[i] = -1;
            }
        } else {
            const int* p = (const int*)ei;
#pragma unroll
            for (int i = 0; i < 8; i++) {
                int e = ebase + i * 256;
                if (e < N_EDGES) {
                    sv[i] = p[e];
                    int d = p[N_EDGES + e];
                    bn[i] = d >> 8; dl[i] = d & 255;
                } else bn[i] = -1;
            }
        }
#pragma unroll
        for (int i = 0; i < 8; i++)
            if (bn[i] >= 0) lr[i] = atomicAdd(&hist[bn[i]], 1);   // LDS atomic
        __syncthreads();
        for (int t = tid; t < NBINS; t += 256) {
            int hc = hist[t];
            curs[t] = hc ? atomicAdd(&binCur[t], hc) : 0;         // 196 global atomics/block
        }
        __syncthreads();
#pragma unroll
        for (int i = 0; i < 8; i++) {
            if (bn[i] >= 0) {
                int pos = curs[bn[i]] + lr[i];
                if (pos < BCAP)
                    packed[bn[i] * BCAP + pos] = sv[i] | (dl[i] << 24);
            }
        }
        return;
    }

    // ---- GEMM ----
    int row0 = blockIdx.x * 128;
    int w    = tid >> 6;
    int lane = tid & 63;
    int quad = lane >> 4;
    int l15  = lane & 15;

    floatx4 acc[2][8];
#pragma unroll
    for (int i = 0; i < 2; i++)
#pragma unroll
        for (int j = 0; j < 8; j++) acc[i][j] = (floatx4){0.f, 0.f, 0.f, 0.f};

    int srow  = tid >> 1;            // 0..127
    int shalf = (tid & 1) * 16;
    const float* xrow = x + (size_t)(row0 + srow) * D_IN;
    bool svalid = (row0 + srow) < N_NODES;

    for (int k0 = 0; k0 < D_IN; k0 += 32) {
        uint4 p0 = make_uint4(0, 0, 0, 0), p1 = make_uint4(0, 0, 0, 0);
        if (svalid) {
            const float* src = xrow + k0 + shalf;
            float4 f0 = *(const float4*)(src + 0);
            float4 f1 = *(const float4*)(src + 4);
            float4 f2 = *(const float4*)(src + 8);
            float4 f3 = *(const float4*)(src + 12);
            p0 = make_uint4(pack2(f0.x, f0.y), pack2(f0.z, f0.w),
                            pack2(f1.x, f1.y), pack2(f1.z, f1.w));
            p1 = make_uint4(pack2(f2.x, f2.y), pack2(f2.z, f2.w),
                            pack2(f3.x, f3.y), pack2(f3.z, f3.w));
        }
        __syncthreads();
        *(uint4*)&As[srow][shalf + 0] = p0;
        *(uint4*)&As[srow][shalf + 8] = p1;
        __syncthreads();

        short8 a0 = *(const short8*)&As[w * 32 + l15][quad * 8];
        short8 a1 = *(const short8*)&As[w * 32 + 16 + l15][quad * 8];
        int kc = k0 >> 5;
#pragma unroll
        for (int ct = 0; ct < 8; ct++) {
            short8 b = *(const short8*)&bf[(size_t)(((ct * 8 + kc) * 64 + lane)) * 8];
            acc[0][ct] = __builtin_amdgcn_mfma_f32_16x16x32_bf16(a0, b, acc[0][ct], 0, 0, 0);
            acc[1][ct] = __builtin_amdgcn_mfma_f32_16x16x32_bf16(a1, b, acc[1][ct], 0, 0, 0);
        }
    }

#pragma unroll
    for (int rt = 0; rt < 2; rt++) {
        int grow0 = row0 + w * 32 + rt * 16 + quad * 4;
#pragma unroll
        for (int r = 0; r < 4; r++) {
            int grow = grow0 + r;
            if (grow < N_NODES) {
#pragma unroll
                for (int ct = 0; ct < 8; ct++) {
                    h[(size_t)grow * D_OUT + ct * 16 + l15] = f2bf(acc[rt][ct][r]);
                }
            }
        }
    }
}

// ---------------------------------------------------------------------------
// D3 ELL build: one block per bin (196 blocks). Reads the bin's packed
// records, assigns slots with LDS counters (zero global atomics), writes
// bucket entries into a contiguous 64KB window (single-XCD L2 accumulation)
// and the dense per-dst cnt.
// ---------------------------------------------------------------------------
__global__ __launch_bounds__(256) void ell_kernel(const int* __restrict__ packed,
                                                  const int* __restrict__ binCur,
                                                  int* __restrict__ cnt,
                                                  int* __restrict__ bucket) {
    __shared__ int c256[256];
    int j = blockIdx.x, tid = threadIdx.x;
    c256[tid] = 0;
    __syncthreads();
    int m = binCur[j];
    if (m > BCAP) m = BCAP;
    const int* seg = packed + j * BCAP;
    for (int i = tid; i < m; i += 256) {
        int rec = seg[i];
        int dl  = ((unsigned int)rec) >> 24;
        int s   = rec & 0xFFFFFF;
        int pos = atomicAdd(&c256[dl], 1);            // LDS atomic
        if (pos < ELL_S) bucket[(size_t)((j << 8) + dl) * ELL_S + pos] = s;
    }
    __syncthreads();
    int d = (j << 8) + tid;
    if (d < N_NODES) cnt[d] = c256[tid];
}

// ---------------------------------------------------------------------------
// D4 gather: 4 dst nodes per wave64 (16 lanes/node, 8 bf16 channels/lane via
// dwordx4 row loads -> each load instruction moves 1 KB serving 4 edges).
// ELL slots preloaded per 16-chunk with the w=0 trick: invalid slots get
// (s=0, w=0) so the edge loop runs to a wave-uniform bound (wave_max) with
// zero divergence; out-of-range slots FMA zero against the L1-hot row 0.
// ---------------------------------------------------------------------------
#define GACC(U, F)                                      \
    a0 += bfl(U.x) * (F); a1 += bfh(U.x) * (F);         \
    a2 += bfl(U.y) * (F); a3 += bfh(U.y) * (F);         \
    a4 += bfl(U.z) * (F); a5 += bfh(U.z) * (F);         \
    a6 += bfl(U.w) * (F); a7 += bfh(U.w) * (F);

#define GBODY(SS, WW, KB)                                                         \
    {                                                                             \
        int lim = wave_max - (KB);                                                \
        if (lim > 16) lim = 16;                                                   \
        for (int k = 0; k < lim; k += 4) {                                        \
            int   s0 = __shfl((SS), gk + k + 0), s1 = __shfl((SS), gk + k + 1);   \
            int   s2 = __shfl((SS), gk + k + 2), s3 = __shfl((SS), gk + k + 3);   \
            float f0 = __shfl((WW), gk + k + 0), f1 = __shfl((WW), gk + k + 1);   \
            float f2 = __shfl((WW), gk + k + 2), f3 = __shfl((WW), gk + k + 3);   \
            uint4 u0 = *(const uint4*)(h + (size_t)s0 * D_OUT + co);              \
            uint4 u1 = *(const uint4*)(h + (size_t)s1 * D_OUT + co);              \
            uint4 u2 = *(const uint4*)(h + (size_t)s2 * D_OUT + co);              \
            uint4 u3 = *(const uint4*)(h + (size_t)s3 * D_OUT + co);              \
            GACC(u0, f0); GACC(u1, f1); GACC(u2, f2); GACC(u3, f3);               \
        }                                                                         \
    }

__global__ __launch_bounds__(256) void gather_kernel(
    const unsigned short* __restrict__ h, const int* __restrict__ cnt,
    const int* __restrict__ bucket, const float* __restrict__ bias,
    const float* __restrict__ pa, float* __restrict__ out) {
    int wave = (int)((blockIdx.x * blockDim.x + threadIdx.x) >> 6);
    int lane = threadIdx.x & 63;
    int g  = lane >> 4;            // node slot within wave (0..3)
    int l  = lane & 15;            // lane within node group
    int gk = g << 4;
    int d  = wave * 4 + g;         // N_NODES % 4 == 0 -> always valid
    if (wave >= N_NODES / 4) return;

    int nraw = cnt[d];
    int n = nraw < ELL_S ? nraw : ELL_S;
    float di = rsqrtf((float)(nraw + 1));

    int co = l * 8;                // channel offset: 8 channels/lane (16 B)

    // self-loop: h[d] * di^2
    uint4 us = *(const uint4*)(h + (size_t)d * D_OUT + co);
    float sl = di * di;
    float a0 = bfl(us.x) * sl, a1 = bfh(us.x) * sl;
    float a2 = bfl(us.y) * sl, a3 = bfh(us.y) * sl;
    float a4 = bfl(us.z) * sl, a5 = bfh(us.z) * sl;
    float a6 = bfl(us.w) * sl, a7 = bfh(us.w) * sl;

    // preload ELL row: 4 chunks of 16 slots; invalid slots get (s=0, w=0)
    int db = d * ELL_S;
    int   s0v = 0,   s1v = 0,   s2v = 0,   s3v = 0;
    float w0v = 0.f, w1v = 0.f, w2v = 0.f, w3v = 0.f;
    if (l      < n) { s0v = bucket[db + l];      w0v = rsqrtf((float)(cnt[s0v] + 1)) * di; }
    if (l + 16 < n) { s1v = bucket[db + l + 16]; w1v = rsqrtf((float)(cnt[s1v] + 1)) * di; }
    if (l + 32 < n) { s2v = bucket[db + l + 32]; w2v = rsqrtf((float)(cnt[s2v] + 1)) * di; }
    if (l + 48 < n) { s3v = bucket[db + l + 48]; w3v = rsqrtf((float)(cnt[s3v] + 1)) * di; }

    // wave-wide max degree -> uniform loop bounds (no divergence in main loop)
    int wave_max = n;
    { int t = __shfl_xor(wave_max, 16); wave_max = t > wave_max ? t : wave_max; }
    { int t = __shfl_xor(wave_max, 32); wave_max = t > wave_max ? t : wave_max; }

    if (wave_max > 0)  GBODY(s0v, w0v, 0)
    if (wave_max > 16) GBODY(s1v, w1v, 16)
    if (wave_max > 32) GBODY(s2v, w2v, 32)
    if (wave_max > 48) GBODY(s3v, w3v, 48)

    int c = l * 8;
    float4 b0 = *(const float4*)&bias[c];
    float4 b1 = *(const float4*)&bias[c + 4];
    float4 p0 = *(const float4*)&pa[c];
    float4 p1 = *(const float4*)&pa[c + 4];
    float4 o0, o1;
    o0.x = a0 + b0.x; o0.y = a1 + b0.y; o0.z = a2 + b0.z; o0.w = a3 + b0.w;
    o1.x = a4 + b1.x; o1.y = a5 + b1.y; o1.z = a6 + b1.z; o1.w = a7 + b1.w;
    o0.x = o0.x > 0.f ? o0.x : p0.x * o0.x;
    o0.y = o0.y > 0.f ? o0.y : p0.y * o0.y;
    o0.z = o0.z > 0.f ? o0.z : p0.z * o0.z;
    o0.w = o0.w > 0.f ? o0.w : p0.w * o0.w;
    o1.x = o1.x > 0.f ? o1.x : p1.x * o1.x;
    o1.y = o1.y > 0.f ? o1.y : p1.y * o1.y;
    o1.z = o1.z > 0.f ? o1.z : p1.z * o1.z;
    o1.w = o1.w > 0.f ? o1.w : p1.w * o1.w;
    *(float4*)&out[(size_t)d * D_OUT + c]     = o0;
    *(float4*)&out[(size_t)d * D_OUT + c + 4] = o1;
}

extern "C" void kernel_launch(void* const* d_in, const int* in_sizes, int n_in,
                              void* d_out, int out_size, void* d_ws, size_t ws_size,
                              hipStream_t stream) {
    const float* x  = (const float*)d_in[0];
    const void*  ei = d_in[1];
    const float* W  = (const float*)d_in[2];
    const float* b  = (const float*)d_in[3];
    const float* pa = (const float*)d_in[4];
    float* out = (float*)d_out;

    char* w = (char*)d_ws;
    int*   is64   = (int*)w;    w += 256;
    int*   binCur = (int*)w;    w += 1024;                                // 196 ints padded
    int*   cnt    = (int*)w;    w += (size_t)CNT_N * 4;                   // 200 KB
    unsigned short* bfrag = (unsigned short*)w; w += 8 * 8 * 64 * 8 * 2;  // 64 KB
    int*   packed = (int*)w;    w += (size_t)NBINS * BCAP * 4;            // 4.0 MB
    int*   bucket = (int*)w;    w += (size_t)N_NODES * ELL_S * 4;         // 12.8 MB
    unsigned short* h = (unsigned short*)w; w += (size_t)N_NODES * D_OUT * 2;

    prep_kernel<<<18, 256, 0, stream>>>((const unsigned int*)ei, is64, W, bfrag, binCur);
    fused_kernel<<<GEMM_BLKS + PART_BLKS, 256, 0, stream>>>(x, bfrag, h, ei, is64, binCur, packed);
    ell_kernel<<<NBINS, 256, 0, stream>>>(packed, binCur, cnt, bucket);
    gather_kernel<<<(N_NODES / 4 * 64 + 255) / 256, 256, 0, stream>>>(h, cnt, bucket, b, pa, out);
}